// Round 1
// baseline (403.022 us; speedup 1.0000x reference)
//
#include <hip/hip_runtime.h>
#include <math.h>

typedef unsigned int uint;
typedef unsigned short ushort;

typedef __attribute__((ext_vector_type(8))) __bf16 bf16x8;
typedef __attribute__((ext_vector_type(16))) float floatx16;

#define NFEAT 327680   // 256*1280 feats elements
#define NW    491520   // 128*3840 W elements
// ws layout: [0, NFEAT) bf16 feats | [NFEAT, NFEAT+NW) bf16 W | 16 floats stats

__device__ inline ushort f2b(float f) {
  uint u = __float_as_uint(f);
  u += 0x7fffu + ((u >> 16) & 1u);   // RNE to bf16
  return (ushort)(u >> 16);
}
__device__ inline float blo(uint u) { return __uint_as_float(u << 16); }
__device__ inline float bhi(uint u) { return __uint_as_float(u & 0xffff0000u); }
__device__ inline uint pack2(float a, float b) {
  return (uint)f2b(a) | ((uint)f2b(b) << 16);
}

// ---------------- prep: fp32 -> bf16 for feats and W, zero stats ----------------
__global__ void prep_kernel(const float* __restrict__ feats,
                            const float* __restrict__ W,
                            ushort* __restrict__ fB,
                            ushort* __restrict__ wB,
                            float* __restrict__ stats) {
  int idx = blockIdx.x * 256 + threadIdx.x;   // 3200*256 = 819200 = NFEAT+NW
  if (blockIdx.x == 0 && threadIdx.x < 16) stats[threadIdx.x] = 0.0f;
  if (idx < NFEAT) fB[idx] = f2b(feats[idx]);
  else             wB[idx - NFEAT] = f2b(W[idx - NFEAT]);
}

// ---------------- fused pair-build + GEMM + stats ----------------
// X[o][m] = sum_k W[o][k] * pair[m][k],  m = i*256+j
// block: 128 o (all) x 128 m (i = blk>>1 fixed, j0 = (blk&1)*128)
// 4 waves in 2x2; wave tile 64o x 64m = 2x2 mfma_32x32x16 tiles
__global__ __launch_bounds__(256, 2) void gemm_kernel(
    const ushort* __restrict__ fB, const ushort* __restrict__ wB,
    const float* __restrict__ bias, float* __restrict__ xout,
    float* __restrict__ stats) {
  __shared__ __align__(16) ushort Wl[128 * 104];  // [o][seg*32+c], +8 pad
  __shared__ __align__(16) ushort Pl[128 * 104];  // [m][seg*32+c], +8 pad

  const int tid = threadIdx.x;
  const int blk = blockIdx.x;         // 0..511
  const int i_row = blk >> 1;
  const int j0 = (blk & 1) << 7;
  const int lane = tid & 63;
  const int w = tid >> 6;
  const int wo = (w >> 1) << 6;       // 0 or 64 (o offset)
  const int wm = (w & 1) << 6;        // 0 or 64 (m offset)
  const int rr = lane & 31;
  const int half = lane >> 5;

  floatx16 acc[2][2];
  #pragma unroll
  for (int a = 0; a < 2; ++a)
    #pragma unroll
    for (int b = 0; b < 2; ++b)
      #pragma unroll
      for (int r = 0; r < 16; ++r) acc[a][b][r] = 0.0f;

  for (int ch = 0; ch < 40; ++ch) {
    const int c0 = ch << 5;
    __syncthreads();
    // stage W chunk: 128 o x 3 seg x 32 c  (1536 16B pieces / 256 threads)
    #pragma unroll
    for (int r6 = 0; r6 < 6; ++r6) {
      int s = tid + (r6 << 8);
      int q = s & 3;
      int row = (s >> 2) & 127;
      int seg = s >> 9;
      uint4 v = *(const uint4*)(wB + row * 3840 + seg * 1280 + c0 + q * 8);
      *(uint4*)(&Wl[row * 104 + seg * 32 + q * 8]) = v;
    }
    // stage pair chunk: 128 j x 32 c raw -> 3 transformed segments
    #pragma unroll
    for (int r2 = 0; r2 < 2; ++r2) {
      int s = tid + (r2 << 8);
      int q = s & 3;
      int row = s >> 2;
      uint4 vj = *(const uint4*)(fB + (j0 + row) * 1280 + c0 + q * 8);
      uint4 vi = *(const uint4*)(fB + i_row * 1280 + c0 + q * 8);
      uint ja[4] = {vj.x, vj.y, vj.z, vj.w};
      uint ia[4] = {vi.x, vi.y, vi.z, vi.w};
      uint oa[4], od[4], oh[4];
      #pragma unroll
      for (int t = 0; t < 4; ++t) {
        float fj0 = blo(ja[t]), fj1 = bhi(ja[t]);
        float fi0 = blo(ia[t]), fi1 = bhi(ia[t]);
        oa[t] = pack2(fi0 + fj0, fi1 + fj1);
        od[t] = pack2(fabsf(fi0 - fj0), fabsf(fi1 - fj1));
        oh[t] = pack2(fi0 * fj0, fi1 * fj1);
      }
      ushort* p = &Pl[row * 104 + q * 8];
      *(uint4*)(p)      = make_uint4(oa[0], oa[1], oa[2], oa[3]);
      *(uint4*)(p + 32) = make_uint4(od[0], od[1], od[2], od[3]);
      *(uint4*)(p + 64) = make_uint4(oh[0], oh[1], oh[2], oh[3]);
    }
    __syncthreads();
    // MFMA over 3 segs x 2 k-steps of 16
    #pragma unroll
    for (int seg = 0; seg < 3; ++seg) {
      #pragma unroll
      for (int ks = 0; ks < 2; ++ks) {
        const int kk = seg * 32 + ks * 16 + half * 8;
        bf16x8 a0 = *(const bf16x8*)(&Wl[(wo + rr) * 104 + kk]);
        bf16x8 a1 = *(const bf16x8*)(&Wl[(wo + 32 + rr) * 104 + kk]);
        bf16x8 b0 = *(const bf16x8*)(&Pl[(wm + rr) * 104 + kk]);
        bf16x8 b1 = *(const bf16x8*)(&Pl[(wm + 32 + rr) * 104 + kk]);
        acc[0][0] = __builtin_amdgcn_mfma_f32_32x32x16_bf16(a0, b0, acc[0][0], 0, 0, 0);
        acc[0][1] = __builtin_amdgcn_mfma_f32_32x32x16_bf16(a0, b1, acc[0][1], 0, 0, 0);
        acc[1][0] = __builtin_amdgcn_mfma_f32_32x32x16_bf16(a1, b0, acc[1][0], 0, 0, 0);
        acc[1][1] = __builtin_amdgcn_mfma_f32_32x32x16_bf16(a1, b1, acc[1][1], 0, 0, 0);
      }
    }
  }

  // epilogue: bias, store x, per-group partial stats
  float gs[2][2] = {{0.f, 0.f}, {0.f, 0.f}};  // [ot][rg]
  float gq[2][2] = {{0.f, 0.f}, {0.f, 0.f}};
  #pragma unroll
  for (int ot = 0; ot < 2; ++ot) {
    const int obase = wo + ot * 32;
    #pragma unroll
    for (int mt = 0; mt < 2; ++mt) {
      const int mglob = (blk << 7) + wm + mt * 32 + rr;
      #pragma unroll
      for (int r = 0; r < 16; ++r) {
        const int orow = (r & 3) + 8 * (r >> 2) + 4 * half;  // D row mapping (m74/m101)
        const int o = obase + orow;
        float x = acc[ot][mt][r] + bias[o];
        xout[o * 65536 + mglob] = x;
        gs[ot][r >> 3] += x;          // r<8 -> rows 0..15, r>=8 -> rows 16..31
        gq[ot][r >> 3] += x * x;
      }
    }
  }
  #pragma unroll
  for (int ot = 0; ot < 2; ++ot) {
    #pragma unroll
    for (int rg = 0; rg < 2; ++rg) {
      float s = gs[ot][rg], q = gq[ot][rg];
      for (int off = 32; off > 0; off >>= 1) {
        s += __shfl_xor(s, off, 64);
        q += __shfl_xor(q, off, 64);
      }
      if (lane == 0) {
        int g = (wo + ot * 32 + rg * 16) >> 4;
        atomicAdd(&stats[g], s);
        atomicAdd(&stats[8 + g], q);
      }
    }
  }
}

// ---------------- groupnorm + exact gelu, in place on d_out ----------------
__global__ void norm_kernel(float* __restrict__ xout,
                            const float* __restrict__ stats,
                            const float* __restrict__ gamma,
                            const float* __restrict__ beta) {
  const int idx = blockIdx.x * 256 + threadIdx.x;
  const int e = idx << 2;           // 4 elements, same channel o (65536 % 4 == 0)
  const int o = e >> 16;
  const int g = o >> 4;
  const float invN = 1.0f / 1048576.0f;  // 16 * 65536 per group
  const float mean = stats[g] * invN;
  const float var = stats[8 + g] * invN - mean * mean;
  const float inv = rsqrtf(var + 1e-5f);
  const float ga = gamma[o], be = beta[o];
  float4 v = *(float4*)(xout + e);
  float* pv = &v.x;
  #pragma unroll
  for (int t = 0; t < 4; ++t) {
    float xn = (pv[t] - mean) * inv * ga + be;
    pv[t] = 0.5f * xn * (1.0f + erff(xn * 0.70710678118654752f));
  }
  *(float4*)(xout + e) = v;
}

extern "C" void kernel_launch(void* const* d_in, const int* in_sizes, int n_in,
                              void* d_out, int out_size, void* d_ws, size_t ws_size,
                              hipStream_t stream) {
  const float* feats = (const float*)d_in[0];
  const float* W     = (const float*)d_in[1];
  const float* bias  = (const float*)d_in[2];
  const float* gamma = (const float*)d_in[3];
  const float* beta  = (const float*)d_in[4];
  float* out = (float*)d_out;

  ushort* fB = (ushort*)d_ws;
  ushort* wB = fB + NFEAT;
  float* stats = (float*)(wB + NW);

  prep_kernel<<<3200, 256, 0, stream>>>(feats, W, fB, wB, stats);
  gemm_kernel<<<512, 256, 0, stream>>>(fB, wB, bias, out, stats);
  norm_kernel<<<8192, 256, 0, stream>>>(out, stats, gamma, beta);
}

// Round 2
// 402.844 us; speedup vs baseline: 1.0004x; 1.0004x over previous
//
#include <hip/hip_runtime.h>
#include <math.h>

typedef unsigned int uint;
typedef unsigned short ushort;

typedef __attribute__((ext_vector_type(8))) __bf16 bf16x8;
typedef __attribute__((ext_vector_type(16))) float floatx16;

#define NFEAT 327680   // 256*1280 feats elements
#define NW    491520   // 128*3840 W elements
// ws layout: [0, NFEAT) bf16 feats | [NFEAT, NFEAT+NW) bf16 W | 16 floats stats

union U4B8 { uint4 u; bf16x8 b; };

__device__ inline ushort f2b(float f) {
  uint u = __float_as_uint(f);
  u += 0x7fffu + ((u >> 16) & 1u);   // RNE to bf16
  return (ushort)(u >> 16);
}
__device__ inline float blo(uint u) { return __uint_as_float(u << 16); }
__device__ inline float bhi(uint u) { return __uint_as_float(u & 0xffff0000u); }
// pack 2 f32 -> 2 bf16 with round-half-up (+0x8000 then take high16 via v_perm)
__device__ inline uint pkrh(float a, float b) {
  uint au = __float_as_uint(a) + 0x8000u;
  uint bu = __float_as_uint(b) + 0x8000u;
  return __builtin_amdgcn_perm(bu, au, 0x07060302u);  // [au.b2,au.b3,bu.b2,bu.b3]
}

// ---------------- prep: fp32 -> bf16 for feats and W, zero stats ----------------
__global__ void prep_kernel(const float* __restrict__ feats,
                            const float* __restrict__ W,
                            ushort* __restrict__ fB,
                            ushort* __restrict__ wB,
                            float* __restrict__ stats) {
  int idx = blockIdx.x * 256 + threadIdx.x;   // 3200*256 = 819200 = NFEAT+NW
  if (blockIdx.x == 0 && threadIdx.x < 16) stats[threadIdx.x] = 0.0f;
  if (idx < NFEAT) fB[idx] = f2b(feats[idx]);
  else             wB[idx - NFEAT] = f2b(W[idx - NFEAT]);
}

// build 3 B-fragments (add/|diff|/had) for one m-tile from fj bits + unpacked fi
__device__ inline void transform(const uint4 vj, const float fi8[8],
                                 uint4& oa, uint4& od, uint4& oh) {
  uint ju[4] = {vj.x, vj.y, vj.z, vj.w};
  uint* pa = &oa.x; uint* pd = &od.x; uint* ph = &oh.x;
  #pragma unroll
  for (int t = 0; t < 4; ++t) {
    float j0 = blo(ju[t]), j1 = bhi(ju[t]);
    float i0 = fi8[2 * t], i1 = fi8[2 * t + 1];
    pa[t] = pkrh(i0 + j0, i1 + j1);
    pd[t] = pkrh(fabsf(i0 - j0), fabsf(i1 - j1));
    ph[t] = pkrh(i0 * j0, i1 * j1);
  }
}

// ---------------- fused pair-build(in-reg) + GEMM + stats ----------------
// X[o][m] = sum_k W[o][k] * pair[m][k],  m = i*256+j
// block: 128 o x 128 m (i = blk>>1, j0 = (blk&1)*128); 4 waves 2x2; wave 64o x 64m
// B-fragments built in registers from fj global loads (no LDS for pair).
// W double-buffered in LDS, 1 barrier per 32-col chunk.
__global__ __launch_bounds__(256, 2) void gemm_kernel(
    const ushort* __restrict__ fB, const ushort* __restrict__ wB,
    const float* __restrict__ bias, float* __restrict__ xout,
    float* __restrict__ stats) {
  __shared__ __align__(16) ushort Wl[2][128 * 104];  // [o][seg*32+c], +8 pad (2-way=free)

  const int tid = threadIdx.x;
  const int blk = blockIdx.x;         // 0..511
  const int i_row = blk >> 1;
  const int j0 = (blk & 1) << 7;
  const int lane = tid & 63;
  const int w = tid >> 6;
  const int wo = (w >> 1) << 6;       // 0 or 64 (o offset)
  const int wm = (w & 1) << 6;        // 0 or 64 (m offset)
  const int rr = lane & 31;
  const int half = lane >> 5;

  // W staging mapping: 1536 16B pieces / 256 threads = 6 each
  const ushort* wgp[6];
  ushort* wlp[6];
  #pragma unroll
  for (int r6 = 0; r6 < 6; ++r6) {
    int s = tid + (r6 << 8);
    int qq = s & 3, row = (s >> 2) & 127, seg = s >> 9;
    wgp[r6] = wB + row * 3840 + seg * 1280 + qq * 8;
    wlp[r6] = &Wl[0][0] + row * 104 + seg * 32 + qq * 8;
  }

  const ushort* fip  = fB + i_row * 1280 + half * 8;
  const ushort* fjp0 = fB + (j0 + wm + rr) * 1280 + half * 8;
  const ushort* fjp1 = fB + (j0 + wm + 32 + rr) * 1280 + half * 8;

  floatx16 acc[2][2];
  #pragma unroll
  for (int a = 0; a < 2; ++a)
    #pragma unroll
    for (int b = 0; b < 2; ++b)
      #pragma unroll
      for (int r = 0; r < 16; ++r) acc[a][b][r] = 0.0f;

  // prologue: stage chunk 0 into buf 0
  #pragma unroll
  for (int r6 = 0; r6 < 6; ++r6) {
    uint4 v = *(const uint4*)(wgp[r6]);
    *(uint4*)(wlp[r6]) = v;
  }
  __syncthreads();

  for (int cc = 0; cc < 40; ++cc) {
    const int cur = cc & 1;
    const ushort* Wc = &Wl[cur][0];
    // prefetch next W chunk into regs (lands during MFMA phase)
    uint4 wreg[6];
    if (cc < 39) {
      const int c0n = (cc + 1) << 5;
      #pragma unroll
      for (int r6 = 0; r6 < 6; ++r6) wreg[r6] = *(const uint4*)(wgp[r6] + c0n);
    }
    // load fi/fj for both 16-col steps of this chunk
    uint4 vi[2], vja[2], vjb[2];
    #pragma unroll
    for (int st = 0; st < 2; ++st) {
      const int c = (cc << 5) + (st << 4);
      vi[st]  = *(const uint4*)(fip + c);
      vja[st] = *(const uint4*)(fjp0 + c);
      vjb[st] = *(const uint4*)(fjp1 + c);
    }
    #pragma unroll
    for (int st = 0; st < 2; ++st) {
      float fi8[8];
      uint iu[4] = {vi[st].x, vi[st].y, vi[st].z, vi[st].w};
      #pragma unroll
      for (int t = 0; t < 4; ++t) { fi8[2*t] = blo(iu[t]); fi8[2*t+1] = bhi(iu[t]); }
      U4B8 b[3][2];
      transform(vja[st], fi8, b[0][0].u, b[1][0].u, b[2][0].u);
      transform(vjb[st], fi8, b[0][1].u, b[1][1].u, b[2][1].u);
      #pragma unroll
      for (int seg = 0; seg < 3; ++seg) {
        const int kk = seg * 32 + (st << 4) + half * 8;
        bf16x8 a0 = *(const bf16x8*)(Wc + (wo + rr) * 104 + kk);
        bf16x8 a1 = *(const bf16x8*)(Wc + (wo + 32 + rr) * 104 + kk);
        acc[0][0] = __builtin_amdgcn_mfma_f32_32x32x16_bf16(a0, b[seg][0].b, acc[0][0], 0, 0, 0);
        acc[0][1] = __builtin_amdgcn_mfma_f32_32x32x16_bf16(a0, b[seg][1].b, acc[0][1], 0, 0, 0);
        acc[1][0] = __builtin_amdgcn_mfma_f32_32x32x16_bf16(a1, b[seg][0].b, acc[1][0], 0, 0, 0);
        acc[1][1] = __builtin_amdgcn_mfma_f32_32x32x16_bf16(a1, b[seg][1].b, acc[1][1], 0, 0, 0);
      }
    }
    // write next chunk to other buffer; readers of cur are pre-barrier, safe
    if (cc < 39) {
      const int boff = (cur ^ 1) * (128 * 104);
      #pragma unroll
      for (int r6 = 0; r6 < 6; ++r6) *(uint4*)(wlp[r6] + boff) = wreg[r6];
    }
    __syncthreads();
  }

  // epilogue: bias, store x, per-group partial stats
  float gs[2][2] = {{0.f, 0.f}, {0.f, 0.f}};
  float gq[2][2] = {{0.f, 0.f}, {0.f, 0.f}};
  #pragma unroll
  for (int ot = 0; ot < 2; ++ot) {
    const int obase = wo + ot * 32;
    #pragma unroll
    for (int mt = 0; mt < 2; ++mt) {
      const int mglob = (blk << 7) + wm + mt * 32 + rr;
      #pragma unroll
      for (int r = 0; r < 16; ++r) {
        const int orow = (r & 3) + 8 * (r >> 2) + 4 * half;  // D row mapping (m74/m101)
        const int o = obase + orow;
        float x = acc[ot][mt][r] + bias[o];
        xout[o * 65536 + mglob] = x;
        gs[ot][r >> 3] += x;
        gq[ot][r >> 3] += x * x;
      }
    }
  }
  #pragma unroll
  for (int ot = 0; ot < 2; ++ot) {
    #pragma unroll
    for (int rg = 0; rg < 2; ++rg) {
      float s = gs[ot][rg], q = gq[ot][rg];
      for (int off = 32; off > 0; off >>= 1) {
        s += __shfl_xor(s, off, 64);
        q += __shfl_xor(q, off, 64);
      }
      if (lane == 0) {
        int g = (wo + ot * 32 + rg * 16) >> 4;
        atomicAdd(&stats[g], s);
        atomicAdd(&stats[8 + g], q);
      }
    }
  }
}

// ---------------- groupnorm + exact gelu, in place on d_out ----------------
__global__ void norm_kernel(float* __restrict__ xout,
                            const float* __restrict__ stats,
                            const float* __restrict__ gamma,
                            const float* __restrict__ beta) {
  const int idx = blockIdx.x * 256 + threadIdx.x;
  const int e = idx << 2;           // 4 elements, same channel o
  const int o = e >> 16;
  const int g = o >> 4;
  const float invN = 1.0f / 1048576.0f;  // 16 * 65536 per group
  const float mean = stats[g] * invN;
  const float var = stats[8 + g] * invN - mean * mean;
  const float inv = rsqrtf(var + 1e-5f);
  const float ga = gamma[o], be = beta[o];
  float4 v = *(float4*)(xout + e);
  float* pv = &v.x;
  #pragma unroll
  for (int t = 0; t < 4; ++t) {
    float xn = (pv[t] - mean) * inv * ga + be;
    pv[t] = 0.5f * xn * (1.0f + erff(xn * 0.70710678118654752f));
  }
  *(float4*)(xout + e) = v;
}

extern "C" void kernel_launch(void* const* d_in, const int* in_sizes, int n_in,
                              void* d_out, int out_size, void* d_ws, size_t ws_size,
                              hipStream_t stream) {
  const float* feats = (const float*)d_in[0];
  const float* W     = (const float*)d_in[1];
  const float* bias  = (const float*)d_in[2];
  const float* gamma = (const float*)d_in[3];
  const float* beta  = (const float*)d_in[4];
  float* out = (float*)d_out;

  ushort* fB = (ushort*)d_ws;
  ushort* wB = fB + NFEAT;
  float* stats = (float*)(wB + NW);

  prep_kernel<<<3200, 256, 0, stream>>>(feats, W, fB, wB, stats);
  gemm_kernel<<<512, 256, 0, stream>>>(fB, wB, bias, out, stats);
  norm_kernel<<<8192, 256, 0, stream>>>(out, stats, gamma, beta);
}

// Round 3
// 195.559 us; speedup vs baseline: 2.0609x; 2.0600x over previous
//
#include <hip/hip_runtime.h>
#include <math.h>

typedef unsigned int uint;
typedef unsigned short ushort;

typedef __attribute__((ext_vector_type(8))) __bf16 bf16x8;
typedef __attribute__((ext_vector_type(16))) float floatx16;

#define NFEAT 327680   // 256*1280 feats elements (bf16)
#define NW    491520   // 128*3840 W elements (bf16)
// ws: fB bf16[NFEAT] | wB bf16[NW] | stats f32[16] | A f32[128*256]

union U4B8 { uint4 u; bf16x8 b; };

__device__ inline ushort f2b(float f) {
  uint u = __float_as_uint(f);
  u += 0x7fffu + ((u >> 16) & 1u);   // RNE to bf16
  return (ushort)(u >> 16);
}
__device__ inline float blo(uint u) { return __uint_as_float(u << 16); }
__device__ inline float bhi(uint u) { return __uint_as_float(u & 0xffff0000u); }
// pack 2 f32 -> 2 bf16, round-half-up (+0x8000, take high16 via v_perm)
__device__ inline uint pkrh(float a, float b) {
  uint au = __float_as_uint(a) + 0x8000u;
  uint bu = __float_as_uint(b) + 0x8000u;
  return __builtin_amdgcn_perm(bu, au, 0x07060302u);
}

// ---------------- prep: fp32 -> bf16, zero stats ----------------
__global__ void prep_kernel(const float* __restrict__ feats,
                            const float* __restrict__ W,
                            ushort* __restrict__ fB,
                            ushort* __restrict__ wB,
                            float* __restrict__ stats) {
  int idx = blockIdx.x * 256 + threadIdx.x;   // 3200*256 = NFEAT+NW
  if (blockIdx.x == 0 && threadIdx.x < 16) stats[threadIdx.x] = 0.0f;
  if (idx < NFEAT) fB[idx] = f2b(feats[idx]);
  else             wB[idx - NFEAT] = f2b(W[idx - NFEAT]);
}

// ---------------- A[o,i] = sum_c Wa[o,c]*f[i,c]  (add-term factor) ----------------
// grid 8 (i-tiles of 32), 256 thr; wave w handles K-quarter [w*320, w*320+320)
__global__ __launch_bounds__(256, 4) void gemma_kernel(
    const ushort* __restrict__ fB, const ushort* __restrict__ wB,
    float* __restrict__ Aoi) {
  __shared__ float red[4][4096];
  const int tid = threadIdx.x, lane = tid & 63, w = tid >> 6;
  const int i0 = blockIdx.x << 5;
  const int rr = lane & 31, half = lane >> 5;
  floatx16 a4[4];
  #pragma unroll
  for (int ot = 0; ot < 4; ++ot)
    #pragma unroll
    for (int r = 0; r < 16; ++r) a4[ot][r] = 0.0f;
  const int kbase = w * 320 + half * 8;
  for (int ks = 0; ks < 20; ++ks) {
    const int k = kbase + ks * 16;
    U4B8 bf; bf.u = *(const uint4*)(fB + (i0 + rr) * 1280 + k);
    #pragma unroll
    for (int ot = 0; ot < 4; ++ot) {
      U4B8 af; af.u = *(const uint4*)(wB + (ot * 32 + rr) * 3840 + k);
      a4[ot] = __builtin_amdgcn_mfma_f32_32x32x16_bf16(af.b, bf.b, a4[ot], 0, 0, 0);
    }
  }
  #pragma unroll
  for (int ot = 0; ot < 4; ++ot)
    #pragma unroll
    for (int r = 0; r < 16; ++r) {
      const int orow = (r & 3) + 8 * (r >> 2) + 4 * half;
      red[w][(ot * 32 + orow) * 32 + rr] = a4[ot][r];
    }
  __syncthreads();
  for (int e = tid; e < 4096; e += 256) {
    float s = red[0][e] + red[1][e] + red[2][e] + red[3][e];
    Aoi[(e >> 5) * 256 + i0 + (e & 31)] = s;
  }
}

// ---------------- main fused GEMM: diff+had terms, K=2560 ----------------
// X[o,m] = sum_c Wd[o,c]|fi-fj|_c + Wh[o,c](fi*fj)_c ; epilogue adds A[o,i]+A[o,j]+b[o]
// grid 1024: i = blk>>2, j0 = (blk&3)*64. 4 waves: (wo in {0,64}) x (wm in {0,32}).
// Wave tile 64o x 32m -> acc 2x16. W dbuf in LDS (stride 72 ush), B built in regs.
__global__ __launch_bounds__(256, 4) void gemm_kernel(
    const ushort* __restrict__ fB, const ushort* __restrict__ wB,
    const float* __restrict__ bias, const float* __restrict__ Aoi,
    float* __restrict__ xout, float* __restrict__ stats) {
  __shared__ __align__(16) ushort Wl[2][128 * 72];  // [o][seg*32+c], stride 72

  const int tid = threadIdx.x;
  const int blk = blockIdx.x;
  const int i_row = blk >> 2;
  const int j0 = (blk & 3) << 6;
  const int lane = tid & 63;
  const int w = tid >> 6;
  const int wo = (w >> 1) << 6;
  const int wm = (w & 1) << 5;
  const int rr = lane & 31;
  const int half = lane >> 5;

  // W staging: 128 rows x 2 segs x 32c = 1024 16B pieces, 4/thread
  // thread -> (row0 = tid>>2, q = tid&3); pieces at row0+{0,64} x seg{0,1}
  const int row0 = tid >> 2, q = tid & 3;
  const ushort* wg = wB + row0 * 3840 + 1280 + q * 8;  // +1280 skips Wa
  ushort* wl = &Wl[0][0] + row0 * 72 + q * 8;
  const int GR = 64 * 3840;   // +64 rows global
  const int LR = 64 * 72;     // +64 rows LDS

  const ushort* fip = fB + i_row * 1280 + half * 8;
  const ushort* fjp = fB + (j0 + wm + rr) * 1280 + half * 8;

  floatx16 acc[2];
  #pragma unroll
  for (int a = 0; a < 2; ++a)
    #pragma unroll
    for (int r = 0; r < 16; ++r) acc[a][r] = 0.0f;

  // prologue: stage chunk 0, preload fi/fj chunk 0
  *(uint4*)(wl)           = *(const uint4*)(wg);
  *(uint4*)(wl + LR)      = *(const uint4*)(wg + GR);
  *(uint4*)(wl + 32)      = *(const uint4*)(wg + 1280);
  *(uint4*)(wl + LR + 32) = *(const uint4*)(wg + GR + 1280);
  uint4 vi[2], vj[2];
  #pragma unroll
  for (int st = 0; st < 2; ++st) {
    vi[st] = *(const uint4*)(fip + st * 16);
    vj[st] = *(const uint4*)(fjp + st * 16);
  }
  __syncthreads();

  for (int cc = 0; cc < 40; ++cc) {
    const int cur = cc & 1;
    const ushort* Wc = &Wl[cur][0];
    uint4 wreg[4], vin[2], vjn[2];
    if (cc < 39) {
      const int cn = (cc + 1) << 5;
      wreg[0] = *(const uint4*)(wg + cn);
      wreg[1] = *(const uint4*)(wg + GR + cn);
      wreg[2] = *(const uint4*)(wg + 1280 + cn);
      wreg[3] = *(const uint4*)(wg + GR + 1280 + cn);
      #pragma unroll
      for (int st = 0; st < 2; ++st) {
        vin[st] = *(const uint4*)(fip + cn + st * 16);
        vjn[st] = *(const uint4*)(fjp + cn + st * 16);
      }
    }
    #pragma unroll
    for (int st = 0; st < 2; ++st) {
      uint ju[4] = {vj[st].x, vj[st].y, vj[st].z, vj[st].w};
      uint iu[4] = {vi[st].x, vi[st].y, vi[st].z, vi[st].w};
      uint du[4], hu[4];
      #pragma unroll
      for (int t = 0; t < 4; ++t) {
        float jf0 = blo(ju[t]), jf1 = bhi(ju[t]);
        float if0 = blo(iu[t]), if1 = bhi(iu[t]);
        du[t] = pkrh(if0 - jf0, if1 - jf1) & 0x7fff7fffu;  // |rhu(x)| == rhu(|x|)
        hu[t] = pkrh(if0 * jf0, if1 * jf1);
      }
      U4B8 dfr, hfr;
      dfr.u = make_uint4(du[0], du[1], du[2], du[3]);
      hfr.u = make_uint4(hu[0], hu[1], hu[2], hu[3]);
      const int ob = st * 16 + half * 8;
      bf16x8 a0d = *(const bf16x8*)(Wc + (wo + rr) * 72 + ob);
      bf16x8 a1d = *(const bf16x8*)(Wc + (wo + 32 + rr) * 72 + ob);
      bf16x8 a0h = *(const bf16x8*)(Wc + (wo + rr) * 72 + 32 + ob);
      bf16x8 a1h = *(const bf16x8*)(Wc + (wo + 32 + rr) * 72 + 32 + ob);
      acc[0] = __builtin_amdgcn_mfma_f32_32x32x16_bf16(a0d, dfr.b, acc[0], 0, 0, 0);
      acc[1] = __builtin_amdgcn_mfma_f32_32x32x16_bf16(a1d, dfr.b, acc[1], 0, 0, 0);
      acc[0] = __builtin_amdgcn_mfma_f32_32x32x16_bf16(a0h, hfr.b, acc[0], 0, 0, 0);
      acc[1] = __builtin_amdgcn_mfma_f32_32x32x16_bf16(a1h, hfr.b, acc[1], 0, 0, 0);
    }
    if (cc < 39) {
      const int bo = (cur ^ 1) * (128 * 72);
      *(uint4*)(wl + bo)           = wreg[0];
      *(uint4*)(wl + bo + LR)      = wreg[1];
      *(uint4*)(wl + bo + 32)      = wreg[2];
      *(uint4*)(wl + bo + LR + 32) = wreg[3];
      vi[0] = vin[0]; vi[1] = vin[1];
      vj[0] = vjn[0]; vj[1] = vjn[1];
    }
    __syncthreads();
  }

  // epilogue: add A[o,i]+A[o,j]+b[o], store x, accumulate group stats
  float gs[2][2] = {{0.f, 0.f}, {0.f, 0.f}};
  float gq[2][2] = {{0.f, 0.f}, {0.f, 0.f}};
  const int jg = j0 + wm + rr;
  const int mglob = i_row * 256 + jg;
  #pragma unroll
  for (int ot = 0; ot < 2; ++ot) {
    #pragma unroll
    for (int r = 0; r < 16; ++r) {
      const int orow = (r & 3) + 8 * (r >> 2) + 4 * half;  // D row map (m74/m101)
      const int o = wo + ot * 32 + orow;
      float x = acc[ot][r] + Aoi[o * 256 + i_row] + Aoi[o * 256 + jg] + bias[o];
      xout[o * 65536 + mglob] = x;
      gs[ot][r >> 3] += x;
      gq[ot][r >> 3] += x * x;
    }
  }
  float* sred = (float*)&Wl[0][0];
  if (tid < 16) sred[tid] = 0.0f;
  __syncthreads();
  #pragma unroll
  for (int ot = 0; ot < 2; ++ot) {
    #pragma unroll
    for (int rg = 0; rg < 2; ++rg) {
      float s = gs[ot][rg], qv = gq[ot][rg];
      for (int off = 32; off > 0; off >>= 1) {
        s += __shfl_xor(s, off, 64);
        qv += __shfl_xor(qv, off, 64);
      }
      if (lane == 0) {
        const int g = (wo >> 4) + ot * 2 + rg;
        atomicAdd(&sred[g], s);
        atomicAdd(&sred[8 + g], qv);
      }
    }
  }
  __syncthreads();
  if (tid < 16) atomicAdd(&stats[tid], sred[tid]);
}

// ---------------- groupnorm + exact gelu, in place ----------------
__global__ void norm_kernel(float* __restrict__ xout,
                            const float* __restrict__ stats,
                            const float* __restrict__ gamma,
                            const float* __restrict__ beta) {
  const int idx = blockIdx.x * 256 + threadIdx.x;
  const int e = idx << 2;
  const int o = e >> 16;
  const int g = o >> 4;
  const float invN = 1.0f / 1048576.0f;  // 16*65536 per group
  const float mean = stats[g] * invN;
  const float var = stats[8 + g] * invN - mean * mean;
  const float inv = rsqrtf(var + 1e-5f);
  const float ga = gamma[o], be = beta[o];
  float4 v = *(float4*)(xout + e);
  float* pv = &v.x;
  #pragma unroll
  for (int t = 0; t < 4; ++t) {
    float xn = (pv[t] - mean) * inv * ga + be;
    pv[t] = 0.5f * xn * (1.0f + erff(xn * 0.70710678118654752f));
  }
  *(float4*)(xout + e) = v;
}

extern "C" void kernel_launch(void* const* d_in, const int* in_sizes, int n_in,
                              void* d_out, int out_size, void* d_ws, size_t ws_size,
                              hipStream_t stream) {
  const float* feats = (const float*)d_in[0];
  const float* W     = (const float*)d_in[1];
  const float* bias  = (const float*)d_in[2];
  const float* gamma = (const float*)d_in[3];
  const float* beta  = (const float*)d_in[4];
  float* out = (float*)d_out;

  ushort* fB = (ushort*)d_ws;
  ushort* wB = fB + NFEAT;
  float* stats = (float*)(wB + NW);
  float* Aoi = stats + 16;

  prep_kernel<<<3200, 256, 0, stream>>>(feats, W, fB, wB, stats);
  gemma_kernel<<<8, 256, 0, stream>>>(fB, wB, Aoi);
  gemm_kernel<<<1024, 256, 0, stream>>>(fB, wB, bias, Aoi, out, stats);
  norm_kernel<<<8192, 256, 0, stream>>>(out, stats, gamma, beta);
}